// Round 1
// baseline (23.768 us; speedup 1.0000x reference)
//
#include <hip/hip_runtime.h>
#include <math.h>

// BeliefPropagation collapse:
// h ∈ {0,1} is used as an INDEX by the reference, so only rows/cols 0,1 of the
// message matrices are live. The whole iteration reduces to a 12-scalar
// recurrence driven by: cnt1[v] = sum_e h[e,v]  (column counts, all v),
// n1[c] = sum_j h[c,j] for c in {0,1}           (row counts, rows 0,1 only),
// base[v] = l_v[v]*b[v], w[v,0], w[v,1], sign[c] = 1-2*s_c[c].
// Final: out[v] = 1/(exp(tanh(0.5*(base[v] + cnt0[v]*C0[v]*w[v,0]
//                                      + cnt1[v]*C1[v]*w[v,1])))+1)
// where C0[v] = mu_cv[0,v] (3-valued: v=0, v=1, v>=2), C1[v] = mu_cv[1,v].

#define V_N 512
#define E_N 256

__device__ inline float ipowf_(float x, int n) {
    // integer power by squaring (mirrors a float product chain closely enough;
    // threshold is 1.4e-2 and these products underflow toward 0 anyway)
    float r = 1.0f, p = x;
    while (n > 0) {
        if (n & 1) r *= p;
        p *= p;
        n >>= 1;
    }
    return r;
}

__global__ __launch_bounds__(1024) void bp_kernel(
    const float* __restrict__ l_v, const int* __restrict__ h,
    const float* __restrict__ s_c, const float* __restrict__ b,
    const float* __restrict__ w, const int* __restrict__ it_p,
    float* __restrict__ out)
{
    const int t = threadIdx.x;
    const int v = t & (V_N - 1);
    const int half = t >> 9;           // 0: rows [0,128), 1: rows [128,256)

    __shared__ int cntsh[1024];
    __shared__ int red0[V_N], red1[V_N];
    __shared__ float csh[8];

    // ---- column partial counts cnt1[v] (coalesced: lane v -> h[e*V + v])
    int part = 0;
    const int ebase = half * (E_N / 2);
    #pragma unroll 8
    for (int e = 0; e < E_N / 2; ++e) {
        part += h[(ebase + e) * V_N + v];
    }
    cntsh[t] = part;

    // ---- row counts n1[0], n1[1] (rows 0 and 1 of h) via LDS tree reduce
    if (half == 0) {
        red0[v] = h[v];
        red1[v] = h[V_N + v];
    }
    __syncthreads();
    for (int off = V_N / 2; off > 0; off >>= 1) {
        if (t < off) { red0[t] += red0[t + off]; red1[t] += red1[t + off]; }
        __syncthreads();
    }

    // ---- 12-scalar recurrence (thread 0), broadcast final mu_cv values
    if (t == 0) {
        const int iters = it_p[0];
        const int n1_0 = red0[0], n1_1 = red1[0];
        const int n0_0 = V_N - n1_0, n0_1 = V_N - n1_1;
        const int cnt1_0 = cntsh[0] + cntsh[V_N + 0];
        const int cnt1_1 = cntsh[1] + cntsh[V_N + 1];
        const int cnt0_0 = E_N - cnt1_0, cnt0_1 = E_N - cnt1_1;
        const float base0 = l_v[0] * b[0];
        const float base1 = l_v[1] * b[1];
        const float w00 = w[0],     w01 = w[1];          // w[0,0], w[0,1]
        const float w10 = w[E_N],   w11 = w[E_N + 1];    // w[1,0], w[1,1]
        const float sg0 = 1.0f - 2.0f * s_c[0];
        const float sg1 = 1.0f - 2.0f * s_c[1];

        // mu_vc rows v=0,1 at columns {0,1,rest}; mu_cv rows c=0,1 at {v0,v1,rest}
        float V0c0 = 0.f, V0c1 = 0.f;
        float V1c0 = 0.f, V1c1 = 0.f;
        float C0v0 = 0.f, C0v1 = 0.f, C0vR = 0.f;
        float C1v0 = 0.f, C1v1 = 0.f, C1vR = 0.f;

        for (int it = 0; it < iters; ++it) {
            // ---- v->c update (reads OLD mu_cv)
            float T0 = (float)cnt0_0 * C0v0 * w00;
            float T1 = (float)cnt1_0 * C1v0 * w01;
            float tot = T0 + T1;
            float nV0c0 = tanhf(0.5f * (base0 + tot - T0));
            float nV0c1 = tanhf(0.5f * (base0 + tot - T1));
            T0 = (float)cnt0_1 * C0v1 * w10;
            T1 = (float)cnt1_1 * C1v1 * w11;
            tot = T0 + T1;
            float nV1c0 = tanhf(0.5f * (base1 + tot - T0));
            float nV1c1 = tanhf(0.5f * (base1 + tot - T1));

            // ---- c->v update (reads OLD mu_vc — Jacobi, matches reference order)
            float t0 = tanhf(0.5f * V0c0);       // c = 0
            float t1 = tanhf(0.5f * V1c0);
            float p0 = ipowf_(t0, n0_0);
            float p1 = ipowf_(t1, n1_0);
            float nC0v0 = sg0 * 2.0f * atanhf(p1);
            float nC0v1 = sg0 * 2.0f * atanhf(p0);
            float nC0vR = sg0 * 2.0f * atanhf(p0 * p1);
            t0 = tanhf(0.5f * V0c1);             // c = 1
            t1 = tanhf(0.5f * V1c1);
            p0 = ipowf_(t0, n0_1);
            p1 = ipowf_(t1, n1_1);
            float nC1v0 = sg1 * 2.0f * atanhf(p1);
            float nC1v1 = sg1 * 2.0f * atanhf(p0);
            float nC1vR = sg1 * 2.0f * atanhf(p0 * p1);

            V0c0 = nV0c0; V0c1 = nV0c1;
            V1c0 = nV1c0; V1c1 = nV1c1;
            C0v0 = nC0v0; C0v1 = nC0v1; C0vR = nC0vR;
            C1v0 = nC1v0; C1v1 = nC1v1; C1vR = nC1vR;
        }
        csh[0] = C0v0; csh[1] = C0v1; csh[2] = C0vR;
        csh[3] = C1v0; csh[4] = C1v1; csh[5] = C1vR;
    }
    __syncthreads();

    // ---- marginalization + output
    if (half == 0) {
        const int cnt1 = cntsh[v] + cntsh[V_N + v];
        const int cnt0 = E_N - cnt1;
        const float basev = l_v[v] * b[v];
        const float wv0 = w[v * E_N + 0];
        const float wv1 = w[v * E_N + 1];
        const float c0 = (v == 0) ? csh[0] : (v == 1) ? csh[1] : csh[2];
        const float c1 = (v == 0) ? csh[3] : (v == 1) ? csh[4] : csh[5];
        const float s = basev + (float)cnt0 * c0 * wv0 + (float)cnt1 * c1 * wv1;
        const float mu = tanhf(0.5f * s);
        out[v] = 1.0f / (expf(mu) + 1.0f);
    }
}

extern "C" void kernel_launch(void* const* d_in, const int* in_sizes, int n_in,
                              void* d_out, int out_size, void* d_ws, size_t ws_size,
                              hipStream_t stream) {
    const float* l_v   = (const float*)d_in[0];
    const int*   h     = (const int*)  d_in[1];
    const float* s_c   = (const float*)d_in[2];
    const float* b     = (const float*)d_in[3];
    const float* w     = (const float*)d_in[4];
    const int*   iters = (const int*)  d_in[5];
    float* out = (float*)d_out;
    hipLaunchKernelGGL(bp_kernel, dim3(1), dim3(1024), 0, stream,
                       l_v, h, s_c, b, w, iters, out);
}